// Round 1
// baseline (525.966 us; speedup 1.0000x reference)
//
#include <hip/hip_runtime.h>
#include <math.h>

#define IN_DIM 512
#define HID 512

#define K1_BLOCKS 1024
#define K1_THREADS 256
#define K1_STRIDE (K1_BLOCKS * K1_THREADS)   // 262144 = 2048*128 -> col4 fixed per thread
#define P1 K1_BLOCKS
#define K2_BLOCKS 64
#define P2 K2_BLOCKS

// K1: partial column sums. Each thread accumulates one fixed float4-column group
// over a grid-stride loop; block reduces 256->128 partials in LDS and writes a
// 512-float partial row (coalesced float4 stores).
__global__ __launch_bounds__(K1_THREADS) void k1_partial(const float* __restrict__ x,
                                                         float* __restrict__ part,
                                                         int total4) {
    const int gtid = blockIdx.x * K1_THREADS + threadIdx.x;
    const float4* __restrict__ x4 = (const float4*)x;
    float4 acc = make_float4(0.f, 0.f, 0.f, 0.f);
    for (int i = gtid; i < total4; i += K1_STRIDE) {
        float4 v = x4[i];
        acc.x += v.x; acc.y += v.y; acc.z += v.z; acc.w += v.w;
    }
    __shared__ float4 lds[K1_THREADS];
    lds[threadIdx.x] = acc;
    __syncthreads();
    if (threadIdx.x < 128) {
        float4 a = lds[threadIdx.x];
        float4 b = lds[threadIdx.x + 128];
        float4 s = make_float4(a.x + b.x, a.y + b.y, a.z + b.z, a.w + b.w);
        // thread t holds column group t (since 256 % 128 == 0)
        ((float4*)(part + (size_t)blockIdx.x * IN_DIM))[threadIdx.x] = s;
    }
}

// K2: reduce 1024 partial rows -> 64 partial rows, fully coalesced.
__global__ __launch_bounds__(IN_DIM) void k2_reduce(const float* __restrict__ part,
                                                    float* __restrict__ part2) {
    const int j = threadIdx.x;
    const int g = blockIdx.x;
    float s = 0.f;
    const int rows = P1 / P2;  // 16
    const float* __restrict__ base = part + (size_t)g * rows * IN_DIM + j;
    for (int r = 0; r < rows; ++r) s += base[(size_t)r * IN_DIM];
    part2[(size_t)g * IN_DIM + j] = s;
}

// K3: finish mean into LDS, then one 64-lane wave per output column computes
// the three gate dot-products + GRU epilogue. h=0 => gh = bias_hh.
__global__ __launch_bounds__(256) void k3_gemv_gates(const float* __restrict__ part2,
                                                     const float* __restrict__ wih,
                                                     const float* __restrict__ bih,
                                                     const float* __restrict__ bhh,
                                                     float* __restrict__ out,
                                                     float inv_n) {
    __shared__ float agg[IN_DIM];
    for (int c = threadIdx.x; c < IN_DIM; c += 256) {
        float s = 0.f;
        for (int r = 0; r < P2; ++r) s += part2[(size_t)r * IN_DIM + c];
        agg[c] = s * inv_n;
    }
    __syncthreads();

    const int w = threadIdx.x >> 6;      // wave in block: 0..3
    const int l = threadIdx.x & 63;      // lane
    const int j = blockIdx.x * 4 + w;    // output column 0..511

    const float4* __restrict__ a4 = (const float4*)agg;
    float4 g1 = a4[l];
    float4 g2 = a4[l + 64];

    float d[3];
#pragma unroll
    for (int gidx = 0; gidx < 3; ++gidx) {
        const float4* __restrict__ w4 =
            (const float4*)(wih + (size_t)(gidx * HID + j) * IN_DIM);
        float4 w1 = w4[l];
        float4 w2 = w4[l + 64];
        d[gidx] = w1.x * g1.x + w1.y * g1.y + w1.z * g1.z + w1.w * g1.w
                + w2.x * g2.x + w2.y * g2.y + w2.z * g2.z + w2.w * g2.w;
    }

#pragma unroll
    for (int off = 32; off > 0; off >>= 1) {
        d[0] += __shfl_down(d[0], off, 64);
        d[1] += __shfl_down(d[1], off, 64);
        d[2] += __shfl_down(d[2], off, 64);
    }

    if (l == 0) {
        float gi_r = d[0] + bih[j];
        float gi_z = d[1] + bih[HID + j];
        float gi_n = d[2] + bih[2 * HID + j];
        float gh_r = bhh[j];
        float gh_z = bhh[HID + j];
        float gh_n = bhh[2 * HID + j];
        float r = 1.f / (1.f + expf(-(gi_r + gh_r)));
        float z = 1.f / (1.f + expf(-(gi_z + gh_z)));
        float n = tanhf(gi_n + r * gh_n);
        out[j] = (1.f - z) * n;   // + z*h, h = 0
    }
}

extern "C" void kernel_launch(void* const* d_in, const int* in_sizes, int n_in,
                              void* d_out, int out_size, void* d_ws, size_t ws_size,
                              hipStream_t stream) {
    const float* x   = (const float*)d_in[0];  // parent_states (N, 512)
    const float* wih = (const float*)d_in[1];  // weight_ih (1536, 512)
    // d_in[2] = weight_hh: unused (h = 0)
    const float* bih = (const float*)d_in[3];  // bias_ih (1536,)
    const float* bhh = (const float*)d_in[4];  // bias_hh (1536,)
    float* out = (float*)d_out;

    const int n_par  = in_sizes[0] / IN_DIM;
    const int total4 = in_sizes[0] / 4;

    float* part  = (float*)d_ws;                      // P1 * 512 floats = 2 MB
    float* part2 = part + (size_t)P1 * IN_DIM;        // P2 * 512 floats = 128 KB

    k1_partial<<<K1_BLOCKS, K1_THREADS, 0, stream>>>(x, part, total4);
    k2_reduce<<<K2_BLOCKS, IN_DIM, 0, stream>>>(part, part2);
    k3_gemv_gates<<<HID / 4, 256, 0, stream>>>(part2, wih, bih, bhh, out,
                                               1.0f / (float)n_par);
}